// Round 6
// baseline (432.429 us; speedup 1.0000x reference)
//
#include <hip/hip_runtime.h>
#include <cstdint>

// AudioXMMDiTCrossAttention: q=x@Wq^T (+per-head RMSNorm*0.125*log2e) via
// 256x256 MFMA GEMM (dbuf LDS, counted vmcnt(8), 2 barriers/K-tile, xor-swizzle);
// k/v from interleaved columns of ctx@[Wk;Wv]^T per the (h d j) reshape,
// k RMSNormed; flash attention attn3: swapped 32x32x16 MFMA, lane-local
// softmax, NO LDS staging (K/V are L2-resident: 128 KB per (b,h), re-read by
// 32 blocks) -> no barriers, fragments loaded global->VGPR directly.

typedef unsigned short u16;
typedef unsigned int u32;
typedef __bf16 bf16x8 __attribute__((ext_vector_type(8)));
typedef float f32x4 __attribute__((ext_vector_type(4)));
typedef float f32x16 __attribute__((ext_vector_type(16)));

__device__ __forceinline__ u16 f2bf(float f) {
  union { float f; unsigned u; } a; a.f = f;
  unsigned r = a.u + 0x7FFFu + ((a.u >> 16) & 1u);
  return (u16)(r >> 16);
}

__device__ __forceinline__ void gload_lds16(const u16* g, u16* l) {
  __builtin_amdgcn_global_load_lds((const __attribute__((address_space(1))) void*)g,
                                   (__attribute__((address_space(3))) void*)l, 16, 0, 0);
}

__global__ __launch_bounds__(256) void cvt_bf16(const float4* __restrict__ in,
                                                uint2* __restrict__ out, int n4) {
  int i = blockIdx.x * 256 + threadIdx.x;
  if (i >= n4) return;
  float4 v = in[i];
  uint2 o;
  o.x = (unsigned)f2bf(v.x) | ((unsigned)f2bf(v.y) << 16);
  o.y = (unsigned)f2bf(v.z) | ((unsigned)f2bf(v.w) << 16);
  out[i] = o;
}

// ---------------------------------------------------------------------------
// 256x256 bf16 GEMM, epilogue = per-64-col RMSNorm * (0.125*log2e) -> bf16
// QN[bh][n][64].  256 blocks x 512 threads.  LDS 128 KiB dbuf; 16B-unit
// xor-swizzle (0 conflicts, verified r4); 2 barriers/K-tile, counted vmcnt(8).
// ---------------------------------------------------------------------------
__global__ __launch_bounds__(512, 2) void qgemm256(const u16* __restrict__ A,
                                                   const u16* __restrict__ B,
                                                   u16* __restrict__ QN) {
  constexpr int K = 2048, T = 32;  // K-tiles of 64
  __shared__ __align__(16) u16 As[2][256 * 64];
  __shared__ __align__(16) u16 Bs[2][256 * 64];
  const int t = threadIdx.x;
  const int wid = t >> 6, l = t & 63;
  const int wr = wid >> 2, wc = wid & 3;
  const int lr = l & 15, lg = l >> 4;
  const int bid = blockIdx.x;
  const int bx = bid >> 3, by = bid & 7;  // XCD-chunked: XCD owns one by (B panel)
  const int brow = bx << 8, bcol = by << 8;

  const int srcu = ((l & 7) ^ (l >> 3)) << 3;
  const int growA = brow + (wid << 3) + (l >> 3);
  const int growB = bcol + (wid << 3) + (l >> 3);

  const int u2k0 = ((lg ^ (l & 7)) << 3);
  const int u2k1 = u2k0 ^ 32;
  const int rbA = (((wr << 7) + lr) << 6);
  const int rbB = (((wc << 6) + lr) << 6);

  f32x4 acc[8][4] = {};

  auto stage = [&](int buf, int half, int kto, bool isB) {
    const u16* gp = isB ? B : A;
    const int grow = (isB ? growB : growA) + (half << 7);
    u16* lb = (isB ? Bs[buf] : As[buf]) + (half << 13) + (wid << 9);
#pragma unroll
    for (int i = 0; i < 2; ++i)
      gload_lds16(gp + (size_t)(grow + (i << 6)) * K + kto + srcu, lb + (i << 12));
  };

  stage(0, 0, 0, false); stage(0, 1, 0, false);
  stage(0, 0, 0, true);  stage(0, 1, 0, true);
  asm volatile("s_waitcnt vmcnt(0)" ::: "memory");
  __builtin_amdgcn_s_barrier();

  for (int tt = 0; tt < T; ++tt) {
    const int bufc = tt & 1, bufn = bufc ^ 1;
    const int kto = (tt + 1) << 6;
    const bool pre = (tt + 1 < T);

    if (pre) {
      stage(bufn, 0, kto, false); stage(bufn, 1, kto, false);
      stage(bufn, 0, kto, true);  stage(bufn, 1, kto, true);
      asm volatile("s_waitcnt vmcnt(8)" ::: "memory");  // bufc's 8 loads done
    } else {
      asm volatile("s_waitcnt vmcnt(0)" ::: "memory");
    }
    __builtin_amdgcn_sched_barrier(0);
    __builtin_amdgcn_s_barrier();
    __builtin_amdgcn_sched_barrier(0);

    bf16x8 bfr[4][2];
#pragma unroll
    for (int ni = 0; ni < 4; ++ni) {
      bfr[ni][0] = *(const bf16x8*)&Bs[bufc][rbB + (ni << 10) + u2k0];
      bfr[ni][1] = *(const bf16x8*)&Bs[bufc][rbB + (ni << 10) + u2k1];
    }
#pragma unroll
    for (int g = 0; g < 4; ++g) {
      bf16x8 af[2][2];
#pragma unroll
      for (int j = 0; j < 2; ++j) {
        af[j][0] = *(const bf16x8*)&As[bufc][rbA + (((g << 1) + j) << 10) + u2k0];
        af[j][1] = *(const bf16x8*)&As[bufc][rbA + (((g << 1) + j) << 10) + u2k1];
      }
#pragma unroll
      for (int j = 0; j < 2; ++j)
#pragma unroll
        for (int ni = 0; ni < 4; ++ni)
#pragma unroll
          for (int kk = 0; kk < 2; ++kk)
            acc[(g << 1) + j][ni] = __builtin_amdgcn_mfma_f32_16x16x32_bf16(
                af[j][kk], bfr[ni][kk], acc[(g << 1) + j][ni], 0, 0, 0);
    }

    __builtin_amdgcn_sched_barrier(0);
    __builtin_amdgcn_s_barrier();
  }

  const int head = (by << 2) + wc;
#pragma unroll
  for (int mi = 0; mi < 8; ++mi) {
#pragma unroll
    for (int r = 0; r < 4; ++r) {
      float ss = 0.f;
#pragma unroll
      for (int ni = 0; ni < 4; ++ni) { float v = acc[mi][ni][r]; ss += v * v; }
      ss += __shfl_xor(ss, 1); ss += __shfl_xor(ss, 2);
      ss += __shfl_xor(ss, 4); ss += __shfl_xor(ss, 8);
      const float sc = rsqrtf(ss * (1.f / 64.f) + 1e-6f) * (0.125f * 1.4426950408889634f);
      const int row = brow + (wr << 7) + (mi << 4) + (lg << 2) + r;
      const int b = row >> 12, n = row & 4095;
      u16* o = QN + ((size_t)((b << 5) + head) * 4096 + n) * 64;
#pragma unroll
      for (int ni = 0; ni < 4; ++ni)
        o[(ni << 4) + lr] = f2bf(acc[mi][ni][r] * sc);
    }
  }
}

// C[row][col] = sum_k A[row][k]*B[col][k]  (bf16 in, fp32 out, ldc col stride)
__global__ __launch_bounds__(256) void gemm_bt(const u16* __restrict__ A,
                                               const u16* __restrict__ B,
                                               float* __restrict__ C, int ldc) {
  constexpr int K = 2048;
  __shared__ __align__(16) u16 As[128 * 32];
  __shared__ __align__(16) u16 Bs[128 * 32];
  const int t = threadIdx.x;
  const int w = t >> 6, l = t & 63;
  const int wr = w >> 1, wc = w & 1;
  const int lr = l & 15, lg = l >> 4;
  const int brow = blockIdx.x << 7, bcol = blockIdx.y << 7;

  f32x4 acc[4][4] = {};

  const int c0 = (w << 6) + l;
  const u16* Ab = A + (size_t)brow * K;
  const u16* Bb = B + (size_t)bcol * K;

  for (int kt = 0; kt < K; kt += 32) {
    __syncthreads();
#pragma unroll
    for (int i = 0; i < 2; ++i) {
      const int c = (i << 8) + c0;
      const int row = c >> 2, koff = (c & 3) << 3;
      gload_lds16(Ab + (size_t)row * K + kt + koff, As + (((i << 8) + (w << 6)) << 3));
      gload_lds16(Bb + (size_t)row * K + kt + koff, Bs + (((i << 8) + (w << 6)) << 3));
    }
    __syncthreads();
    bf16x8 af[4], bfr[4];
#pragma unroll
    for (int mi = 0; mi < 4; ++mi)
      af[mi] = *(const bf16x8*)&As[(((wr << 6) + (mi << 4) + lr) << 5) + (lg << 3)];
#pragma unroll
    for (int ni = 0; ni < 4; ++ni)
      bfr[ni] = *(const bf16x8*)&Bs[(((wc << 6) + (ni << 4) + lr) << 5) + (lg << 3)];
#pragma unroll
    for (int mi = 0; mi < 4; ++mi)
#pragma unroll
      for (int ni = 0; ni < 4; ++ni)
        acc[mi][ni] = __builtin_amdgcn_mfma_f32_16x16x32_bf16(af[mi], bfr[ni], acc[mi][ni], 0, 0, 0);
  }

#pragma unroll
  for (int mi = 0; mi < 4; ++mi)
#pragma unroll
    for (int r = 0; r < 4; ++r) {
      const int row = brow + (wr << 6) + (mi << 4) + (lg << 2) + r;
      float* o = C + (size_t)row * ldc + bcol + (wc << 6);
#pragma unroll
      for (int ni = 0; ni < 4; ++ni)
        o[(ni << 4) + lr] = acc[mi][ni][r];
    }
}

// kv: (b*512+m) x 4096 fp32, cols [0,2048)=ctx@Wk^T, [2048,4096)=ctx@Wv^T.
// k[b,h,m,d] = kv[b,m, sel + 128*(h&15) + 2d], v = +1 (sel = 0 or 2048 by h<16).
// kn[bh][m][d] = bf16(RMSNorm(k)); vtn[bh][d][m] = bf16(v) via LDS transpose.
__global__ __launch_bounds__(256) void kvbuild2(const float* __restrict__ kv,
                                                u16* __restrict__ kn,
                                                u16* __restrict__ vtn) {
  __shared__ u16 Vl[64][72];
  const int t = threadIdx.x;
  const int bh = blockIdx.x >> 3, mt = blockIdx.x & 7;
  const int b = bh >> 5, h = bh & 31;
  const int mloc = t >> 2, dc = (t & 3) << 4;
  const int m = (mt << 6) + mloc;
  const float2* src = (const float2*)(kv + ((size_t)((b << 9) + m)) * 4096 + ((h >> 4) << 11))
                      + ((h & 15) << 6) + dc;
  float kvals[16], vvals[16];
  float ss = 0.f;
#pragma unroll
  for (int dd = 0; dd < 16; ++dd) {
    float2 p = src[dd];
    kvals[dd] = p.x; vvals[dd] = p.y;
    ss += p.x * p.x;
  }
  ss += __shfl_xor(ss, 1); ss += __shfl_xor(ss, 2);
  const float sc = rsqrtf(ss * (1.f / 64.f) + 1e-6f);
  union { uint4 u4[2]; u16 h[16]; } ko;
#pragma unroll
  for (int dd = 0; dd < 16; ++dd) ko.h[dd] = f2bf(kvals[dd] * sc);
  u16* kdst = kn + ((size_t)bh * 512 + m) * 64 + dc;
  *(uint4*)kdst = ko.u4[0];
  *(uint4*)(kdst + 8) = ko.u4[1];
#pragma unroll
  for (int dd = 0; dd < 16; ++dd) Vl[dc + dd][mloc] = f2bf(vvals[dd]);
  __syncthreads();
  const int drow = t >> 2, mc = (t & 3) << 4;
  uint4 r0 = *(const uint4*)&Vl[drow][mc];
  uint4 r1 = *(const uint4*)&Vl[drow][mc + 8];
  u16* vdst = vtn + ((size_t)(bh << 6) + drow) * 512 + (mt << 6) + mc;
  *(uint4*)vdst = r0;
  *(uint4*)(vdst + 8) = r1;
}

// Flash attention, swapped operands: S^T = mfma32(K,Q) so lane owns one q-row.
// Block = 4 independent waves x 32 q-rows = 128 rows of one (b,h); m tiled 64.
// NO LDS staging: K/V fragments loaded global->VGPR (L2-resident), no barriers.
__global__ __launch_bounds__(256) void attn3(const u16* __restrict__ qn,
                                             const u16* __restrict__ kn,
                                             const u16* __restrict__ vtn,
                                             float* __restrict__ out) {
  const int t = threadIdx.x, w = t >> 6, l = t & 63;
  const int i31 = l & 31, hi = l >> 5;
  const int nblk = blockIdx.x, bh = blockIdx.y;
  const int b = bh >> 5, h = bh & 31;
  const int qrow = (nblk << 7) + (w << 5) + i31;

  // Q as B-operand: lane needs Q[i=i31][d = 16*kt + 8*hi + jj]
  const u16* qb = qn + ((size_t)bh * 4096 + qrow) * 64 + (hi << 3);
  bf16x8 bq[4];
#pragma unroll
  for (int kt = 0; kt < 4; ++kt) bq[kt] = *(const bf16x8*)(qb + (kt << 4));

  f32x16 po[2];
#pragma unroll
  for (int d = 0; d < 2; ++d)
#pragma unroll
    for (int r = 0; r < 16; ++r) po[d][r] = 0.f;
  float mrun = -3e38f, lrun = 0.f;

  // K rows for this lane: kn[bh][mt*64 + jt*32 + i31][kt*16 + hi*8]
  const u16* kr = kn + ((size_t)((bh << 9) + i31)) * 64 + (hi << 3);
  // V rows: vtn[bh][dt*32 + i31][mt*64 + kk*16 + hi*8]
  const u16* vr = vtn + ((size_t)((bh << 6) + i31)) * 512 + (hi << 3);

  for (int mt = 0; mt < 8; ++mt) {
    // ---- QK^T: S^T[j][i] = mfma32(K-frag, Q-frag); j' = (reg&3)+8*(reg>>2)+4*hi
    f32x16 fs[2];
#pragma unroll
    for (int jt = 0; jt < 2; ++jt) {
      const u16* krow = kr + (size_t)((mt << 6) + (jt << 5)) * 64;
      f32x16 s = {};
#pragma unroll
      for (int kt = 0; kt < 4; ++kt) {
        const bf16x8 ak = *(const bf16x8*)(krow + (kt << 4));
        s = __builtin_amdgcn_mfma_f32_32x32x16_bf16(ak, bq[kt], s, 0, 0, 0);
      }
      fs[jt] = s;
    }

    // ---- lane-local softmax for q-row i31 (halves exchange via shfl 32)
    float pm = fs[0][0];
#pragma unroll
    for (int r = 1; r < 16; ++r) pm = fmaxf(pm, fs[0][r]);
#pragma unroll
    for (int r = 0; r < 16; ++r) pm = fmaxf(pm, fs[1][r]);
    pm = fmaxf(pm, __shfl_xor(pm, 32));
    if (!__all(pm <= mrun + 8.f)) {  // defer-max (log2 units)
      const float mnew = fmaxf(mrun, pm);
      const float corr = exp2f(mrun - mnew);
      lrun *= corr;
#pragma unroll
      for (int d = 0; d < 2; ++d)
#pragma unroll
        for (int r = 0; r < 16; ++r) po[d][r] *= corr;
      mrun = mnew;
    }
    float rs = 0.f;
    u32 pq[2][4][2];
#pragma unroll
    for (int jt = 0; jt < 2; ++jt)
#pragma unroll
      for (int q = 0; q < 4; ++q)
#pragma unroll
        for (int rp = 0; rp < 2; ++rp) {
          const float p0 = exp2f(fs[jt][(q << 2) + (rp << 1)] - mrun);
          const float p1 = exp2f(fs[jt][(q << 2) + (rp << 1) + 1] - mrun);
          rs += p0 + p1;
          union { u32 u; __bf16 h2[2]; } pk;
          pk.h2[0] = (__bf16)p0;
          pk.h2[1] = (__bf16)p1;
          pq[jt][q][rp] = pk.u;
        }
    rs += __shfl_xor(rs, 32);
    lrun += rs;

    // ---- PV: P^T B-frags + V fragments from global
#pragma unroll
    for (int kk = 0; kk < 4; ++kk) {
      const int jt = kk >> 1, q0 = (kk & 1) << 1;
      union { u32 wd[4]; bf16x8 v; } pf;
#pragma unroll
      for (int rp = 0; rp < 2; ++rp) {
        const u32 v0 = pq[jt][q0][rp], v1 = pq[jt][q0 + 1][rp];
        const u32 send = hi ? v0 : v1;
        const u32 ex = (u32)__shfl_xor((int)send, 32);
        pf.wd[rp] = hi ? ex : v0;
        pf.wd[2 + rp] = hi ? v1 : ex;
      }
#pragma unroll
      for (int dt = 0; dt < 2; ++dt) {
        const bf16x8 av = *(const bf16x8*)(vr + (size_t)(dt << 14) + (mt << 6) + (kk << 4));
        po[dt] = __builtin_amdgcn_mfma_f32_32x32x16_bf16(av, pf.v, po[dt], 0, 0, 0);
      }
    }
  }

  const float inv = 1.f / lrun;
  float* ob = out + ((size_t)(b << 12) + qrow) * 2048 + (h << 6) + (hi << 2);
#pragma unroll
  for (int dt = 0; dt < 2; ++dt)
#pragma unroll
    for (int q = 0; q < 4; ++q) {
      float4 v = { po[dt][(q << 2)] * inv, po[dt][(q << 2) + 1] * inv,
                   po[dt][(q << 2) + 2] * inv, po[dt][(q << 2) + 3] * inv };
      *(float4*)(ob + (dt << 5) + (q << 3)) = v;
    }
}

extern "C" void kernel_launch(void* const* d_in, const int* in_sizes, int n_in,
                              void* d_out, int out_size, void* d_ws, size_t ws_size,
                              hipStream_t stream) {
  const float* x   = (const float*)d_in[0];
  const float* ctx = (const float*)d_in[1];
  const float* Wq  = (const float*)d_in[2];
  const float* Wk  = (const float*)d_in[3];
  const float* Wv  = (const float*)d_in[4];
  float* out = (float*)d_out;
  char* ws = (char*)d_ws;

  // ws layout (bytes); kvraw/kn/vtn reuse xb's region after the q-GEMM.
  u16* xb   = (u16*)(ws + 0);          // 33,554,432
  u16* cb   = (u16*)(ws + 33554432);   //  4,194,304
  u16* Wqb  = (u16*)(ws + 37748736);   //  8,388,608
  u16* Wkb  = (u16*)(ws + 46137344);   //  8,388,608 (Wvb contiguous after)
  u16* Wvb  = (u16*)(ws + 54525952);   //  8,388,608
  u16* qnp  = (u16*)(ws + 62914560);   // 33,554,432 (ends 96,468,992)
  float* kvraw = (float*)(ws + 0);       // 16,777,216 (1024 x 4096 fp32)
  u16* knp  = (u16*)(ws + 16777216);     //  4,194,304
  u16* vtnp = (u16*)(ws + 20971520);     //  4,194,304

  cvt_bf16<<<16384, 256, 0, stream>>>((const float4*)x,   (uint2*)xb,  4194304);
  cvt_bf16<<<2048,  256, 0, stream>>>((const float4*)ctx, (uint2*)cb,   524288);
  cvt_bf16<<<4096,  256, 0, stream>>>((const float4*)Wq,  (uint2*)Wqb, 1048576);
  cvt_bf16<<<4096,  256, 0, stream>>>((const float4*)Wk,  (uint2*)Wkb, 1048576);
  cvt_bf16<<<4096,  256, 0, stream>>>((const float4*)Wv,  (uint2*)Wvb, 1048576);

  qgemm256<<<256, 512, 0, stream>>>(xb, Wqb, qnp);
  gemm_bt<<<dim3(8, 32), 256, 0, stream>>>(cb, Wkb, kvraw, 4096);
  kvbuild2<<<512, 256, 0, stream>>>(kvraw, knp, vtnp);
  attn3<<<dim3(32, 64), 256, 0, stream>>>(qnp, knp, vtnp, out);
}

// Round 7
// 359.898 us; speedup vs baseline: 1.2015x; 1.2015x over previous
//
#include <hip/hip_runtime.h>
#include <cstdint>

// AudioXMMDiTCrossAttention: q=x@Wq^T (+per-head RMSNorm*0.125*log2e) via
// 256x256 MFMA GEMM (dbuf LDS, counted vmcnt(8), 2 barriers/K-tile, xor-swizzle);
// k/v from interleaved columns of ctx@[Wk;Wv]^T per the (h d j) reshape,
// k RMSNormed; flash attention attn4: LDS-staged K/V (attn3's no-LDS variant
// was latency-bound: 64-line scatters), swapped 32x32x16 MFMA, lane-local
// softmax WITHOUT max-tracking: RMSNorm bounds |S*log2e*scale| <= 11.54, so
// exp2(S) in [3e-4, 2976] is fp32/bf16-safe and softmax is shift-invariant.

typedef unsigned short u16;
typedef unsigned int u32;
typedef __bf16 bf16x8 __attribute__((ext_vector_type(8)));
typedef float f32x4 __attribute__((ext_vector_type(4)));
typedef float f32x16 __attribute__((ext_vector_type(16)));

__device__ __forceinline__ u16 f2bf(float f) {
  union { float f; unsigned u; } a; a.f = f;
  unsigned r = a.u + 0x7FFFu + ((a.u >> 16) & 1u);
  return (u16)(r >> 16);
}

__device__ __forceinline__ void gload_lds16(const u16* g, u16* l) {
  __builtin_amdgcn_global_load_lds((const __attribute__((address_space(1))) void*)g,
                                   (__attribute__((address_space(3))) void*)l, 16, 0, 0);
}

__global__ __launch_bounds__(256) void cvt_bf16(const float4* __restrict__ in,
                                                uint2* __restrict__ out, int n4) {
  int i = blockIdx.x * 256 + threadIdx.x;
  if (i >= n4) return;
  float4 v = in[i];
  uint2 o;
  o.x = (unsigned)f2bf(v.x) | ((unsigned)f2bf(v.y) << 16);
  o.y = (unsigned)f2bf(v.z) | ((unsigned)f2bf(v.w) << 16);
  out[i] = o;
}

// ---------------------------------------------------------------------------
// 256x256 bf16 GEMM, epilogue = per-64-col RMSNorm * (0.125*log2e) -> bf16
// QN[bh][n][64].  256 blocks x 512 threads.  LDS 128 KiB dbuf; 16B-unit
// xor-swizzle (0 conflicts); 2 barriers/K-tile, counted vmcnt(8).
// ---------------------------------------------------------------------------
__global__ __launch_bounds__(512, 2) void qgemm256(const u16* __restrict__ A,
                                                   const u16* __restrict__ B,
                                                   u16* __restrict__ QN) {
  constexpr int K = 2048, T = 32;  // K-tiles of 64
  __shared__ __align__(16) u16 As[2][256 * 64];
  __shared__ __align__(16) u16 Bs[2][256 * 64];
  const int t = threadIdx.x;
  const int wid = t >> 6, l = t & 63;
  const int wr = wid >> 2, wc = wid & 3;
  const int lr = l & 15, lg = l >> 4;
  const int bid = blockIdx.x;
  const int bx = bid >> 3, by = bid & 7;  // XCD-chunked: XCD owns one by (B panel)
  const int brow = bx << 8, bcol = by << 8;

  const int srcu = ((l & 7) ^ (l >> 3)) << 3;
  const int growA = brow + (wid << 3) + (l >> 3);
  const int growB = bcol + (wid << 3) + (l >> 3);

  const int u2k0 = ((lg ^ (l & 7)) << 3);
  const int u2k1 = u2k0 ^ 32;
  const int rbA = (((wr << 7) + lr) << 6);
  const int rbB = (((wc << 6) + lr) << 6);

  f32x4 acc[8][4] = {};

  auto stage = [&](int buf, int half, int kto, bool isB) {
    const u16* gp = isB ? B : A;
    const int grow = (isB ? growB : growA) + (half << 7);
    u16* lb = (isB ? Bs[buf] : As[buf]) + (half << 13) + (wid << 9);
#pragma unroll
    for (int i = 0; i < 2; ++i)
      gload_lds16(gp + (size_t)(grow + (i << 6)) * K + kto + srcu, lb + (i << 12));
  };

  stage(0, 0, 0, false); stage(0, 1, 0, false);
  stage(0, 0, 0, true);  stage(0, 1, 0, true);
  asm volatile("s_waitcnt vmcnt(0)" ::: "memory");
  __builtin_amdgcn_s_barrier();

  for (int tt = 0; tt < T; ++tt) {
    const int bufc = tt & 1, bufn = bufc ^ 1;
    const int kto = (tt + 1) << 6;
    const bool pre = (tt + 1 < T);

    if (pre) {
      stage(bufn, 0, kto, false); stage(bufn, 1, kto, false);
      stage(bufn, 0, kto, true);  stage(bufn, 1, kto, true);
      asm volatile("s_waitcnt vmcnt(8)" ::: "memory");  // bufc's 8 loads done
    } else {
      asm volatile("s_waitcnt vmcnt(0)" ::: "memory");
    }
    __builtin_amdgcn_sched_barrier(0);
    __builtin_amdgcn_s_barrier();
    __builtin_amdgcn_sched_barrier(0);

    bf16x8 bfr[4][2];
#pragma unroll
    for (int ni = 0; ni < 4; ++ni) {
      bfr[ni][0] = *(const bf16x8*)&Bs[bufc][rbB + (ni << 10) + u2k0];
      bfr[ni][1] = *(const bf16x8*)&Bs[bufc][rbB + (ni << 10) + u2k1];
    }
#pragma unroll
    for (int g = 0; g < 4; ++g) {
      bf16x8 af[2][2];
#pragma unroll
      for (int j = 0; j < 2; ++j) {
        af[j][0] = *(const bf16x8*)&As[bufc][rbA + (((g << 1) + j) << 10) + u2k0];
        af[j][1] = *(const bf16x8*)&As[bufc][rbA + (((g << 1) + j) << 10) + u2k1];
      }
#pragma unroll
      for (int j = 0; j < 2; ++j)
#pragma unroll
        for (int ni = 0; ni < 4; ++ni)
#pragma unroll
          for (int kk = 0; kk < 2; ++kk)
            acc[(g << 1) + j][ni] = __builtin_amdgcn_mfma_f32_16x16x32_bf16(
                af[j][kk], bfr[ni][kk], acc[(g << 1) + j][ni], 0, 0, 0);
    }

    __builtin_amdgcn_sched_barrier(0);
    __builtin_amdgcn_s_barrier();
  }

  const int head = (by << 2) + wc;
#pragma unroll
  for (int mi = 0; mi < 8; ++mi) {
#pragma unroll
    for (int r = 0; r < 4; ++r) {
      float ss = 0.f;
#pragma unroll
      for (int ni = 0; ni < 4; ++ni) { float v = acc[mi][ni][r]; ss += v * v; }
      ss += __shfl_xor(ss, 1); ss += __shfl_xor(ss, 2);
      ss += __shfl_xor(ss, 4); ss += __shfl_xor(ss, 8);
      const float sc = rsqrtf(ss * (1.f / 64.f) + 1e-6f) * (0.125f * 1.4426950408889634f);
      const int row = brow + (wr << 7) + (mi << 4) + (lg << 2) + r;
      const int b = row >> 12, n = row & 4095;
      u16* o = QN + ((size_t)((b << 5) + head) * 4096 + n) * 64;
#pragma unroll
      for (int ni = 0; ni < 4; ++ni)
        o[(ni << 4) + lr] = f2bf(acc[mi][ni][r] * sc);
    }
  }
}

// C[row][col] = sum_k A[row][k]*B[col][k]  (bf16 in, fp32 out, ldc col stride)
__global__ __launch_bounds__(256) void gemm_bt(const u16* __restrict__ A,
                                               const u16* __restrict__ B,
                                               float* __restrict__ C, int ldc) {
  constexpr int K = 2048;
  __shared__ __align__(16) u16 As[128 * 32];
  __shared__ __align__(16) u16 Bs[128 * 32];
  const int t = threadIdx.x;
  const int w = t >> 6, l = t & 63;
  const int wr = w >> 1, wc = w & 1;
  const int lr = l & 15, lg = l >> 4;
  const int brow = blockIdx.x << 7, bcol = blockIdx.y << 7;

  f32x4 acc[4][4] = {};

  const int c0 = (w << 6) + l;
  const u16* Ab = A + (size_t)brow * K;
  const u16* Bb = B + (size_t)bcol * K;

  for (int kt = 0; kt < K; kt += 32) {
    __syncthreads();
#pragma unroll
    for (int i = 0; i < 2; ++i) {
      const int c = (i << 8) + c0;
      const int row = c >> 2, koff = (c & 3) << 3;
      gload_lds16(Ab + (size_t)row * K + kt + koff, As + (((i << 8) + (w << 6)) << 3));
      gload_lds16(Bb + (size_t)row * K + kt + koff, Bs + (((i << 8) + (w << 6)) << 3));
    }
    __syncthreads();
    bf16x8 af[4], bfr[4];
#pragma unroll
    for (int mi = 0; mi < 4; ++mi)
      af[mi] = *(const bf16x8*)&As[(((wr << 6) + (mi << 4) + lr) << 5) + (lg << 3)];
#pragma unroll
    for (int ni = 0; ni < 4; ++ni)
      bfr[ni] = *(const bf16x8*)&Bs[(((wc << 6) + (ni << 4) + lr) << 5) + (lg << 3)];
#pragma unroll
    for (int mi = 0; mi < 4; ++mi)
#pragma unroll
      for (int ni = 0; ni < 4; ++ni)
        acc[mi][ni] = __builtin_amdgcn_mfma_f32_16x16x32_bf16(af[mi], bfr[ni], acc[mi][ni], 0, 0, 0);
  }

#pragma unroll
  for (int mi = 0; mi < 4; ++mi)
#pragma unroll
    for (int r = 0; r < 4; ++r) {
      const int row = brow + (wr << 6) + (mi << 4) + (lg << 2) + r;
      float* o = C + (size_t)row * ldc + bcol + (wc << 6);
#pragma unroll
      for (int ni = 0; ni < 4; ++ni)
        o[(ni << 4) + lr] = acc[mi][ni][r];
    }
}

// kv: (b*512+m) x 4096 fp32, cols [0,2048)=ctx@Wk^T, [2048,4096)=ctx@Wv^T.
// k[b,h,m,d] = kv[b,m, sel + 128*(h&15) + 2d], v = +1 (sel = 0 or 2048 by h<16).
// kn[bh][m][d] = bf16(RMSNorm(k)); vtn[bh][d][m] = bf16(v) via LDS transpose.
__global__ __launch_bounds__(256) void kvbuild2(const float* __restrict__ kv,
                                                u16* __restrict__ kn,
                                                u16* __restrict__ vtn) {
  __shared__ u16 Vl[64][72];
  const int t = threadIdx.x;
  const int bh = blockIdx.x >> 3, mt = blockIdx.x & 7;
  const int b = bh >> 5, h = bh & 31;
  const int mloc = t >> 2, dc = (t & 3) << 4;
  const int m = (mt << 6) + mloc;
  const float2* src = (const float2*)(kv + ((size_t)((b << 9) + m)) * 4096 + ((h >> 4) << 11))
                      + ((h & 15) << 6) + dc;
  float kvals[16], vvals[16];
  float ss = 0.f;
#pragma unroll
  for (int dd = 0; dd < 16; ++dd) {
    float2 p = src[dd];
    kvals[dd] = p.x; vvals[dd] = p.y;
    ss += p.x * p.x;
  }
  ss += __shfl_xor(ss, 1); ss += __shfl_xor(ss, 2);
  const float sc = rsqrtf(ss * (1.f / 64.f) + 1e-6f);
  union { uint4 u4[2]; u16 h[16]; } ko;
#pragma unroll
  for (int dd = 0; dd < 16; ++dd) ko.h[dd] = f2bf(kvals[dd] * sc);
  u16* kdst = kn + ((size_t)bh * 512 + m) * 64 + dc;
  *(uint4*)kdst = ko.u4[0];
  *(uint4*)(kdst + 8) = ko.u4[1];
#pragma unroll
  for (int dd = 0; dd < 16; ++dd) Vl[dc + dd][mloc] = f2bf(vvals[dd]);
  __syncthreads();
  const int drow = t >> 2, mc = (t & 3) << 4;
  uint4 r0 = *(const uint4*)&Vl[drow][mc];
  uint4 r1 = *(const uint4*)&Vl[drow][mc + 8];
  u16* vdst = vtn + ((size_t)(bh << 6) + drow) * 512 + (mt << 6) + mc;
  *(uint4*)vdst = r0;
  *(uint4*)(vdst + 8) = r1;
}

// Flash attention, swapped operands: S^T = mfma32(K,Q) so lane owns one q-row.
// Block = 4 waves x 32 q-rows = 128 rows of one (b,h); m tiled by 64.
// LDS-staged K/V (pad 68: 2-way bank aliasing = free); softmax WITHOUT
// max-tracking (RMSNorm bounds |S_log2| <= 11.54 -> exp2 range fp32/bf16-safe).
__global__ __launch_bounds__(256) void attn4(const u16* __restrict__ qn,
                                             const u16* __restrict__ kn,
                                             const u16* __restrict__ vtn,
                                             float* __restrict__ out) {
  __shared__ __align__(16) u16 Kt[64 * 68];  // [j][d] pad 68
  __shared__ __align__(16) u16 Vt[64 * 68];  // [d][m] pad 68
  const int t = threadIdx.x, w = t >> 6, l = t & 63;
  const int i31 = l & 31, hi = l >> 5;
  const int nblk = blockIdx.x, bh = blockIdx.y;
  const int b = bh >> 5, h = bh & 31;
  const int qrow = (nblk << 7) + (w << 5) + i31;

  // Q as B-operand: lane needs Q[i=i31][d = 16*kt + 8*hi + jj]
  const u16* qb = qn + ((size_t)bh * 4096 + qrow) * 64 + (hi << 3);
  bf16x8 bq[4];
#pragma unroll
  for (int kt = 0; kt < 4; ++kt) bq[kt] = *(const bf16x8*)(qb + (kt << 4));

  f32x16 po[2];
#pragma unroll
  for (int d = 0; d < 2; ++d)
#pragma unroll
    for (int r = 0; r < 16; ++r) po[d][r] = 0.f;
  float lrun = 0.f;

  const u16* kb = kn + ((size_t)bh << 9) * 64;
  const u16* vb = vtn + ((size_t)bh << 6) * 512;
  const int srow = t >> 2, sp = (t & 3) << 3;

  for (int mt = 0; mt < 8; ++mt) {
    __syncthreads();
    {  // stage K-tile [64][64] and V^T-tile [64][64] (coalesced 16B loads)
      const u16* gk = kb + (size_t)((mt << 6) + srow) * 64 + sp;
      uint4 a0 = *(const uint4*)gk;
      uint4 a1 = *(const uint4*)(gk + 32);
      const u16* gv = vb + (size_t)srow * 512 + (mt << 6) + sp;
      uint4 b0 = *(const uint4*)gv;
      uint4 b1 = *(const uint4*)(gv + 32);
      *(uint4*)&Kt[srow * 68 + sp] = a0;
      *(uint4*)&Kt[srow * 68 + sp + 32] = a1;
      *(uint4*)&Vt[srow * 68 + sp] = b0;
      *(uint4*)&Vt[srow * 68 + sp + 32] = b1;
    }
    __syncthreads();

    // S^T[j][i]: A=K-frag rows j, B=Q. Lane holds j' = (reg&3)+8*(reg>>2)+4*hi.
    f32x16 fs[2];
    __builtin_amdgcn_s_setprio(1);
#pragma unroll
    for (int jt = 0; jt < 2; ++jt) {
      f32x16 s = {};
#pragma unroll
      for (int kt = 0; kt < 4; ++kt) {
        const bf16x8 ak = *(const bf16x8*)&Kt[((jt << 5) + i31) * 68 + (kt << 4) + (hi << 3)];
        s = __builtin_amdgcn_mfma_f32_32x32x16_bf16(ak, bq[kt], s, 0, 0, 0);
      }
      fs[jt] = s;
    }
    __builtin_amdgcn_s_setprio(0);

    // shift-free softmax: p = exp2(S_log2) directly (|S_log2| <= 11.54)
    float rs = 0.f;
    u32 pq[2][4][2];
#pragma unroll
    for (int jt = 0; jt < 2; ++jt)
#pragma unroll
      for (int q = 0; q < 4; ++q)
#pragma unroll
        for (int rp = 0; rp < 2; ++rp) {
          const float p0 = exp2f(fs[jt][(q << 2) + (rp << 1)]);
          const float p1 = exp2f(fs[jt][(q << 2) + (rp << 1) + 1]);
          rs += p0 + p1;
          union { u32 u; __bf16 h2[2]; } pk;
          pk.h2[0] = (__bf16)p0;
          pk.h2[1] = (__bf16)p1;
          pq[jt][q][rp] = pk.u;
        }
    rs += __shfl_xor(rs, 32);
    lrun += rs;

    // P^T B-frags: word(kk,w) = pq[kk>>1][2*(kk&1)+hi][w&1] from lane (i31, w>>1)
    __builtin_amdgcn_s_setprio(1);
#pragma unroll
    for (int kk = 0; kk < 4; ++kk) {
      const int jt = kk >> 1, q0 = (kk & 1) << 1;
      union { u32 wd[4]; bf16x8 v; } pf;
#pragma unroll
      for (int rp = 0; rp < 2; ++rp) {
        const u32 v0 = pq[jt][q0][rp], v1 = pq[jt][q0 + 1][rp];
        const u32 send = hi ? v0 : v1;
        const u32 ex = (u32)__shfl_xor((int)send, 32);
        pf.wd[rp] = hi ? ex : v0;
        pf.wd[2 + rp] = hi ? v1 : ex;
      }
#pragma unroll
      for (int dt = 0; dt < 2; ++dt) {
        const bf16x8 av = *(const bf16x8*)&Vt[((dt << 5) + i31) * 68 + (kk << 4) + (hi << 3)];
        po[dt] = __builtin_amdgcn_mfma_f32_32x32x16_bf16(av, pf.v, po[dt], 0, 0, 0);
      }
    }
    __builtin_amdgcn_s_setprio(0);
  }

  const float inv = 1.f / lrun;
  float* ob = out + ((size_t)(b << 12) + qrow) * 2048 + (h << 6) + (hi << 2);
#pragma unroll
  for (int dt = 0; dt < 2; ++dt)
#pragma unroll
    for (int q = 0; q < 4; ++q) {
      float4 v = { po[dt][(q << 2)] * inv, po[dt][(q << 2) + 1] * inv,
                   po[dt][(q << 2) + 2] * inv, po[dt][(q << 2) + 3] * inv };
      *(float4*)(ob + (dt << 5) + (q << 3)) = v;
    }
}

extern "C" void kernel_launch(void* const* d_in, const int* in_sizes, int n_in,
                              void* d_out, int out_size, void* d_ws, size_t ws_size,
                              hipStream_t stream) {
  const float* x   = (const float*)d_in[0];
  const float* ctx = (const float*)d_in[1];
  const float* Wq  = (const float*)d_in[2];
  const float* Wk  = (const float*)d_in[3];
  const float* Wv  = (const float*)d_in[4];
  float* out = (float*)d_out;
  char* ws = (char*)d_ws;

  // ws layout (bytes); kvraw/kn/vtn reuse xb's region after the q-GEMM.
  u16* xb   = (u16*)(ws + 0);          // 33,554,432
  u16* cb   = (u16*)(ws + 33554432);   //  4,194,304
  u16* Wqb  = (u16*)(ws + 37748736);   //  8,388,608
  u16* Wkb  = (u16*)(ws + 46137344);   //  8,388,608 (Wvb contiguous after)
  u16* Wvb  = (u16*)(ws + 54525952);   //  8,388,608
  u16* qnp  = (u16*)(ws + 62914560);   // 33,554,432 (ends 96,468,992)
  float* kvraw = (float*)(ws + 0);       // 16,777,216 (1024 x 4096 fp32)
  u16* knp  = (u16*)(ws + 16777216);     //  4,194,304
  u16* vtnp = (u16*)(ws + 20971520);     //  4,194,304

  cvt_bf16<<<16384, 256, 0, stream>>>((const float4*)x,   (uint2*)xb,  4194304);
  cvt_bf16<<<2048,  256, 0, stream>>>((const float4*)ctx, (uint2*)cb,   524288);
  cvt_bf16<<<4096,  256, 0, stream>>>((const float4*)Wq,  (uint2*)Wqb, 1048576);
  cvt_bf16<<<4096,  256, 0, stream>>>((const float4*)Wk,  (uint2*)Wkb, 1048576);
  cvt_bf16<<<4096,  256, 0, stream>>>((const float4*)Wv,  (uint2*)Wvb, 1048576);

  qgemm256<<<256, 512, 0, stream>>>(xb, Wqb, qnp);
  gemm_bt<<<dim3(8, 32), 256, 0, stream>>>(cb, Wkb, kvraw, 4096);
  kvbuild2<<<512, 256, 0, stream>>>(kvraw, knp, vtnp);
  attn4<<<dim3(32, 64), 256, 0, stream>>>(qnp, knp, vtnp, out);
}

// Round 11
// 346.644 us; speedup vs baseline: 1.2475x; 1.0382x over previous
//
#include <hip/hip_runtime.h>
#include <cstdint>

// AudioXMMDiTCrossAttention: q=x@Wq^T (+per-head RMSNorm*0.125*log2e) via
// 256x256 MFMA GEMM (dbuf LDS, counted vmcnt(8), 2 barriers/K-tile,
// xor-swizzle, 1-quadrant-ahead ds_read pipeline + setprio);
// k/v from interleaved columns of ctx@[Wk;Wv]^T per the (h d j) reshape,
// k RMSNormed; flash attention attn4 (LDS-staged K/V pad-68, swapped
// 32x32x16 MFMA, shift-free softmax: RMSNorm bounds |S_log2|<=11.54).
// All 5 fp32->bf16 converts fused into one kernel (contiguous dst in ws).
// [3rd resubmission of round-7 kernel: benches lost to GPUAcquisitionTimeout.]

typedef unsigned short u16;
typedef unsigned int u32;
typedef __bf16 bf16x8 __attribute__((ext_vector_type(8)));
typedef float f32x4 __attribute__((ext_vector_type(4)));
typedef float f32x16 __attribute__((ext_vector_type(16)));

__device__ __forceinline__ u16 f2bf(float f) {
  union { float f; unsigned u; } a; a.f = f;
  unsigned r = a.u + 0x7FFFu + ((a.u >> 16) & 1u);
  return (u16)(r >> 16);
}

__device__ __forceinline__ void gload_lds16(const u16* g, u16* l) {
  __builtin_amdgcn_global_load_lds((const __attribute__((address_space(1))) void*)g,
                                   (__attribute__((address_space(3))) void*)l, 16, 0, 0);
}

// One fused convert for x, ctx, Wq, Wk, Wv -> bf16 regions contiguous at ws+0.
// Region sizes in float4 units: 4194304, 524288, 1048576, 1048576, 1048576.
__global__ __launch_bounds__(256) void cvt_all(const float4* __restrict__ x,
                                               const float4* __restrict__ ctx,
                                               const float4* __restrict__ wq,
                                               const float4* __restrict__ wk,
                                               const float4* __restrict__ wv,
                                               uint2* __restrict__ dst) {
  const int i = blockIdx.x * 256 + threadIdx.x;  // < 7864320
  const float4* s;
  int off;
  if (i < 4194304)      { s = x;   off = 0; }
  else if (i < 4718592) { s = ctx; off = 4194304; }
  else if (i < 5767168) { s = wq;  off = 4718592; }
  else if (i < 6815744) { s = wk;  off = 5767168; }
  else                  { s = wv;  off = 6815744; }
  float4 v = s[i - off];
  uint2 o;
  o.x = (unsigned)f2bf(v.x) | ((unsigned)f2bf(v.y) << 16);
  o.y = (unsigned)f2bf(v.z) | ((unsigned)f2bf(v.w) << 16);
  dst[i] = o;
}

// ---------------------------------------------------------------------------
// 256x256 bf16 GEMM, epilogue = per-64-col RMSNorm * (0.125*log2e) -> bf16
// QN[bh][n][64].  256 blocks x 512 threads.  LDS 128 KiB dbuf; 16B-unit
// xor-swizzle (0 conflicts); 2 barriers/K-tile, counted vmcnt(8); compute
// region uses an explicit 1-quadrant-ahead ds_read pipeline: A-quadrant g+1
// reads issue before quadrant g's MFMAs (compiler emits counted lgkmcnt(4),
// so reads fly under MFMAs); sched_barrier(0) fences pin the order.
// ---------------------------------------------------------------------------
#define READ_QUAD(dst, mi0)                                                    \
  _Pragma("unroll")                                                            \
  for (int j = 0; j < 2; ++j) {                                                \
    dst[j][0] = *(const bf16x8*)&As[bufc][rbA + (((mi0) + j) << 10) + u2k0];   \
    dst[j][1] = *(const bf16x8*)&As[bufc][rbA + (((mi0) + j) << 10) + u2k1];   \
  }

#define MFMA_QUAD(src, mi0)                                                    \
  __builtin_amdgcn_s_setprio(1);                                               \
  _Pragma("unroll")                                                            \
  for (int j = 0; j < 2; ++j)                                                  \
    _Pragma("unroll")                                                          \
    for (int ni = 0; ni < 4; ++ni)                                             \
      _Pragma("unroll")                                                        \
      for (int kk = 0; kk < 2; ++kk)                                           \
        acc[(mi0) + j][ni] = __builtin_amdgcn_mfma_f32_16x16x32_bf16(          \
            src[j][kk], bfr[ni][kk], acc[(mi0) + j][ni], 0, 0, 0);             \
  __builtin_amdgcn_s_setprio(0);

__global__ __launch_bounds__(512, 2) void qgemm256(const u16* __restrict__ A,
                                                   const u16* __restrict__ B,
                                                   u16* __restrict__ QN) {
  constexpr int K = 2048, T = 32;  // K-tiles of 64
  __shared__ __align__(16) u16 As[2][256 * 64];
  __shared__ __align__(16) u16 Bs[2][256 * 64];
  const int t = threadIdx.x;
  const int wid = t >> 6, l = t & 63;
  const int wr = wid >> 2, wc = wid & 3;
  const int lr = l & 15, lg = l >> 4;
  const int bid = blockIdx.x;
  const int bx = bid >> 3, by = bid & 7;  // XCD-chunked: XCD owns one by (B panel)
  const int brow = bx << 8, bcol = by << 8;

  const int srcu = ((l & 7) ^ (l >> 3)) << 3;
  const int growA = brow + (wid << 3) + (l >> 3);
  const int growB = bcol + (wid << 3) + (l >> 3);

  const int u2k0 = ((lg ^ (l & 7)) << 3);
  const int u2k1 = u2k0 ^ 32;
  const int rbA = (((wr << 7) + lr) << 6);
  const int rbB = (((wc << 6) + lr) << 6);

  f32x4 acc[8][4] = {};

  auto stage = [&](int buf, int half, int kto, bool isB) {
    const u16* gp = isB ? B : A;
    const int grow = (isB ? growB : growA) + (half << 7);
    u16* lb = (isB ? Bs[buf] : As[buf]) + (half << 13) + (wid << 9);
#pragma unroll
    for (int i = 0; i < 2; ++i)
      gload_lds16(gp + (size_t)(grow + (i << 6)) * K + kto + srcu, lb + (i << 12));
  };

  stage(0, 0, 0, false); stage(0, 1, 0, false);
  stage(0, 0, 0, true);  stage(0, 1, 0, true);
  asm volatile("s_waitcnt vmcnt(0)" ::: "memory");
  __builtin_amdgcn_s_barrier();

  for (int tt = 0; tt < T; ++tt) {
    const int bufc = tt & 1, bufn = bufc ^ 1;
    const int kto = (tt + 1) << 6;
    const bool pre = (tt + 1 < T);

    if (pre) {
      stage(bufn, 0, kto, false); stage(bufn, 1, kto, false);
      stage(bufn, 0, kto, true);  stage(bufn, 1, kto, true);
      asm volatile("s_waitcnt vmcnt(8)" ::: "memory");  // bufc's 8 loads done
    } else {
      asm volatile("s_waitcnt vmcnt(0)" ::: "memory");
    }
    __builtin_amdgcn_sched_barrier(0);
    __builtin_amdgcn_s_barrier();   // all waves' bufc contributions visible
    __builtin_amdgcn_sched_barrier(0);

    // ---- compute bufc: 1-quadrant-ahead pipeline ----
    bf16x8 bfr[4][2];
#pragma unroll
    for (int ni = 0; ni < 4; ++ni) {
      bfr[ni][0] = *(const bf16x8*)&Bs[bufc][rbB + (ni << 10) + u2k0];
      bfr[ni][1] = *(const bf16x8*)&Bs[bufc][rbB + (ni << 10) + u2k1];
    }
    bf16x8 afA[2][2], afB[2][2];
    READ_QUAD(afA, 0)
    __builtin_amdgcn_sched_barrier(0);
    READ_QUAD(afB, 2)
    __builtin_amdgcn_sched_barrier(0);
    MFMA_QUAD(afA, 0)                  // waits bfr+afA; afB in flight
    __builtin_amdgcn_sched_barrier(0);
    READ_QUAD(afA, 4)
    __builtin_amdgcn_sched_barrier(0);
    MFMA_QUAD(afB, 2)                  // afA(q2) in flight
    __builtin_amdgcn_sched_barrier(0);
    READ_QUAD(afB, 6)
    __builtin_amdgcn_sched_barrier(0);
    MFMA_QUAD(afA, 4)                  // afB(q3) in flight
    __builtin_amdgcn_sched_barrier(0);
    MFMA_QUAD(afB, 6)

    __builtin_amdgcn_sched_barrier(0);
    __builtin_amdgcn_s_barrier();   // trailing: all done reading bufc
  }

  // ---- epilogue: per-head RMSNorm (wave's 64 cols = one head), bf16 write
  const int head = (by << 2) + wc;
#pragma unroll
  for (int mi = 0; mi < 8; ++mi) {
#pragma unroll
    for (int r = 0; r < 4; ++r) {
      float ss = 0.f;
#pragma unroll
      for (int ni = 0; ni < 4; ++ni) { float v = acc[mi][ni][r]; ss += v * v; }
      ss += __shfl_xor(ss, 1); ss += __shfl_xor(ss, 2);
      ss += __shfl_xor(ss, 4); ss += __shfl_xor(ss, 8);
      const float sc = rsqrtf(ss * (1.f / 64.f) + 1e-6f) * (0.125f * 1.4426950408889634f);
      const int row = brow + (wr << 7) + (mi << 4) + (lg << 2) + r;
      const int b = row >> 12, n = row & 4095;
      u16* o = QN + ((size_t)((b << 5) + head) * 4096 + n) * 64;
#pragma unroll
      for (int ni = 0; ni < 4; ++ni)
        o[(ni << 4) + lr] = f2bf(acc[mi][ni][r] * sc);
    }
  }
}

// C[row][col] = sum_k A[row][k]*B[col][k]  (bf16 in, fp32 out, ldc col stride)
__global__ __launch_bounds__(256) void gemm_bt(const u16* __restrict__ A,
                                               const u16* __restrict__ B,
                                               float* __restrict__ C, int ldc) {
  constexpr int K = 2048;
  __shared__ __align__(16) u16 As[128 * 32];
  __shared__ __align__(16) u16 Bs[128 * 32];
  const int t = threadIdx.x;
  const int w = t >> 6, l = t & 63;
  const int wr = w >> 1, wc = w & 1;
  const int lr = l & 15, lg = l >> 4;
  const int brow = blockIdx.x << 7, bcol = blockIdx.y << 7;

  f32x4 acc[4][4] = {};

  const int c0 = (w << 6) + l;
  const u16* Ab = A + (size_t)brow * K;
  const u16* Bb = B + (size_t)bcol * K;

  for (int kt = 0; kt < K; kt += 32) {
    __syncthreads();
#pragma unroll
    for (int i = 0; i < 2; ++i) {
      const int c = (i << 8) + c0;
      const int row = c >> 2, koff = (c & 3) << 3;
      gload_lds16(Ab + (size_t)row * K + kt + koff, As + (((i << 8) + (w << 6)) << 3));
      gload_lds16(Bb + (size_t)row * K + kt + koff, Bs + (((i << 8) + (w << 6)) << 3));
    }
    __syncthreads();
    bf16x8 af[4], bfr[4];
#pragma unroll
    for (int mi = 0; mi < 4; ++mi)
      af[mi] = *(const bf16x8*)&As[(((wr << 6) + (mi << 4) + lr) << 5) + (lg << 3)];
#pragma unroll
    for (int ni = 0; ni < 4; ++ni)
      bfr[ni] = *(const bf16x8*)&Bs[(((wc << 6) + (ni << 4) + lr) << 5) + (lg << 3)];
#pragma unroll
    for (int mi = 0; mi < 4; ++mi)
#pragma unroll
      for (int ni = 0; ni < 4; ++ni)
        acc[mi][ni] = __builtin_amdgcn_mfma_f32_16x16x32_bf16(af[mi], bfr[ni], acc[mi][ni], 0, 0, 0);
  }

#pragma unroll
  for (int mi = 0; mi < 4; ++mi)
#pragma unroll
    for (int r = 0; r < 4; ++r) {
      const int row = brow + (wr << 6) + (mi << 4) + (lg << 2) + r;
      float* o = C + (size_t)row * ldc + bcol + (wc << 6);
#pragma unroll
      for (int ni = 0; ni < 4; ++ni)
        o[(ni << 4) + lr] = acc[mi][ni][r];
    }
}

// kv: (b*512+m) x 4096 fp32, cols [0,2048)=ctx@Wk^T, [2048,4096)=ctx@Wv^T.
// k[b,h,m,d] = kv[b,m, sel + 128*(h&15) + 2d], v = +1 (sel = 0 or 2048 by h<16).
// kn[bh][m][d] = bf16(RMSNorm(k)); vtn[bh][d][m] = bf16(v) via LDS transpose.
__global__ __launch_bounds__(256) void kvbuild2(const float* __restrict__ kv,
                                                u16* __restrict__ kn,
                                                u16* __restrict__ vtn) {
  __shared__ u16 Vl[64][72];
  const int t = threadIdx.x;
  const int bh = blockIdx.x >> 3, mt = blockIdx.x & 7;
  const int b = bh >> 5, h = bh & 31;
  const int mloc = t >> 2, dc = (t & 3) << 4;
  const int m = (mt << 6) + mloc;
  const float2* src = (const float2*)(kv + ((size_t)((b << 9) + m)) * 4096 + ((h >> 4) << 11))
                      + ((h & 15) << 6) + dc;
  float kvals[16], vvals[16];
  float ss = 0.f;
#pragma unroll
  for (int dd = 0; dd < 16; ++dd) {
    float2 p = src[dd];
    kvals[dd] = p.x; vvals[dd] = p.y;
    ss += p.x * p.x;
  }
  ss += __shfl_xor(ss, 1); ss += __shfl_xor(ss, 2);
  const float sc = rsqrtf(ss * (1.f / 64.f) + 1e-6f);
  union { uint4 u4[2]; u16 h[16]; } ko;
#pragma unroll
  for (int dd = 0; dd < 16; ++dd) ko.h[dd] = f2bf(kvals[dd] * sc);
  u16* kdst = kn + ((size_t)bh * 512 + m) * 64 + dc;
  *(uint4*)kdst = ko.u4[0];
  *(uint4*)(kdst + 8) = ko.u4[1];
#pragma unroll
  for (int dd = 0; dd < 16; ++dd) Vl[dc + dd][mloc] = f2bf(vvals[dd]);
  __syncthreads();
  const int drow = t >> 2, mc = (t & 3) << 4;
  uint4 r0 = *(const uint4*)&Vl[drow][mc];
  uint4 r1 = *(const uint4*)&Vl[drow][mc + 8];
  u16* vdst = vtn + ((size_t)(bh << 6) + drow) * 512 + (mt << 6) + mc;
  *(uint4*)vdst = r0;
  *(uint4*)(vdst + 8) = r1;
}

// Flash attention, swapped operands: S^T = mfma32(K,Q) so lane owns one q-row.
// Block = 4 waves x 32 q-rows = 128 rows of one (b,h); m tiled by 64.
// LDS-staged K/V (pad 68: 2-way bank aliasing = free); softmax WITHOUT
// max-tracking (RMSNorm bounds |S_log2| <= 11.54 -> exp2 range fp32/bf16-safe).
__global__ __launch_bounds__(256) void attn4(const u16* __restrict__ qn,
                                             const u16* __restrict__ kn,
                                             const u16* __restrict__ vtn,
                                             float* __restrict__ out) {
  __shared__ __align__(16) u16 Kt[64 * 68];  // [j][d] pad 68
  __shared__ __align__(16) u16 Vt[64 * 68];  // [d][m] pad 68
  const int t = threadIdx.x, w = t >> 6, l = t & 63;
  const int i31 = l & 31, hi = l >> 5;
  const int nblk = blockIdx.x, bh = blockIdx.y;
  const int b = bh >> 5, h = bh & 31;
  const int qrow = (nblk << 7) + (w << 5) + i31;

  // Q as B-operand: lane needs Q[i=i31][d = 16*kt + 8*hi + jj]
  const u16* qb = qn + ((size_t)bh * 4096 + qrow) * 64 + (hi << 3);
  bf16x8 bq[4];
#pragma unroll
  for (int kt = 0; kt < 4; ++kt) bq[kt] = *(const bf16x8*)(qb + (kt << 4));

  f32x16 po[2];
#pragma unroll
  for (int d = 0; d < 2; ++d)
#pragma unroll
    for (int r = 0; r < 16; ++r) po[d][r] = 0.f;
  float lrun = 0.f;

  const u16* kb = kn + ((size_t)bh << 9) * 64;
  const u16* vb = vtn + ((size_t)bh << 6) * 512;
  const int srow = t >> 2, sp = (t & 3) << 3;

  for (int mt = 0; mt < 8; ++mt) {
    __syncthreads();
    {  // stage K-tile [64][64] and V^T-tile [64][64] (coalesced 16B loads)
      const u16* gk = kb + (size_t)((mt << 6) + srow) * 64 + sp;
      uint4 a0 = *(const uint4*)gk;
      uint4 a1 = *(const uint4*)(gk + 32);
      const u16* gv = vb + (size_t)srow * 512 + (mt << 6) + sp;
      uint4 b0 = *(const uint4*)gv;
      uint4 b1 = *(const uint4*)(gv + 32);
      *(uint4*)&Kt[srow * 68 + sp] = a0;
      *(uint4*)&Kt[srow * 68 + sp + 32] = a1;
      *(uint4*)&Vt[srow * 68 + sp] = b0;
      *(uint4*)&Vt[srow * 68 + sp + 32] = b1;
    }
    __syncthreads();

    // S^T[j][i]: A=K-frag rows j, B=Q. Lane holds j' = (reg&3)+8*(reg>>2)+4*hi.
    f32x16 fs[2];
    __builtin_amdgcn_s_setprio(1);
#pragma unroll
    for (int jt = 0; jt < 2; ++jt) {
      f32x16 s = {};
#pragma unroll
      for (int kt = 0; kt < 4; ++kt) {
        const bf16x8 ak = *(const bf16x8*)&Kt[((jt << 5) + i31) * 68 + (kt << 4) + (hi << 3)];
        s = __builtin_amdgcn_mfma_f32_32x32x16_bf16(ak, bq[kt], s, 0, 0, 0);
      }
      fs[jt] = s;
    }
    __builtin_amdgcn_s_setprio(0);

    // shift-free softmax: p = exp2(S_log2) directly (|S_log2| <= 11.54)
    float rs = 0.f;
    u32 pq[2][4][2];
#pragma unroll
    for (int jt = 0; jt < 2; ++jt)
#pragma unroll
      for (int q = 0; q < 4; ++q)
#pragma unroll
        for (int rp = 0; rp < 2; ++rp) {
          const float p0 = exp2f(fs[jt][(q << 2) + (rp << 1)]);
          const float p1 = exp2f(fs[jt][(q << 2) + (rp << 1) + 1]);
          rs += p0 + p1;
          union { u32 u; __bf16 h2[2]; } pk;
          pk.h2[0] = (__bf16)p0;
          pk.h2[1] = (__bf16)p1;
          pq[jt][q][rp] = pk.u;
        }
    rs += __shfl_xor(rs, 32);
    lrun += rs;

    // P^T B-frags: word(kk,w) = pq[kk>>1][2*(kk&1)+hi][w&1] from lane (i31, w>>1)
    __builtin_amdgcn_s_setprio(1);
#pragma unroll
    for (int kk = 0; kk < 4; ++kk) {
      const int jt = kk >> 1, q0 = (kk & 1) << 1;
      union { u32 wd[4]; bf16x8 v; } pf;
#pragma unroll
      for (int rp = 0; rp < 2; ++rp) {
        const u32 v0 = pq[jt][q0][rp], v1 = pq[jt][q0 + 1][rp];
        const u32 send = hi ? v0 : v1;
        const u32 ex = (u32)__shfl_xor((int)send, 32);
        pf.wd[rp] = hi ? ex : v0;
        pf.wd[2 + rp] = hi ? v1 : ex;
      }
#pragma unroll
      for (int dt = 0; dt < 2; ++dt) {
        const bf16x8 av = *(const bf16x8*)&Vt[((dt << 5) + i31) * 68 + (kk << 4) + (hi << 3)];
        po[dt] = __builtin_amdgcn_mfma_f32_32x32x16_bf16(av, pf.v, po[dt], 0, 0, 0);
      }
    }
    __builtin_amdgcn_s_setprio(0);
  }

  const float inv = 1.f / lrun;
  float* ob = out + ((size_t)(b << 12) + qrow) * 2048 + (h << 6) + (hi << 2);
#pragma unroll
  for (int dt = 0; dt < 2; ++dt)
#pragma unroll
    for (int q = 0; q < 4; ++q) {
      float4 v = { po[dt][(q << 2)] * inv, po[dt][(q << 2) + 1] * inv,
                   po[dt][(q << 2) + 2] * inv, po[dt][(q << 2) + 3] * inv };
      *(float4*)(ob + (dt << 5) + (q << 3)) = v;
    }
}

extern "C" void kernel_launch(void* const* d_in, const int* in_sizes, int n_in,
                              void* d_out, int out_size, void* d_ws, size_t ws_size,
                              hipStream_t stream) {
  const float* x   = (const float*)d_in[0];
  const float* ctx = (const float*)d_in[1];
  const float* Wq  = (const float*)d_in[2];
  const float* Wk  = (const float*)d_in[3];
  const float* Wv  = (const float*)d_in[4];
  float* out = (float*)d_out;
  char* ws = (char*)d_ws;

  // ws layout (bytes); kvraw/kn/vtn reuse xb's region after the q-GEMM.
  u16* xb   = (u16*)(ws + 0);          // 33,554,432
  u16* cb   = (u16*)(ws + 33554432);   //  4,194,304
  u16* Wqb  = (u16*)(ws + 37748736);   //  8,388,608
  u16* Wkb  = (u16*)(ws + 46137344);   //  8,388,608 (Wvb contiguous after)
  u16* qnp  = (u16*)(ws + 62914560);   // 33,554,432 (ends 96,468,992)
  float* kvraw = (float*)(ws + 0);       // 16,777,216 (1024 x 4096 fp32)
  u16* knp  = (u16*)(ws + 16777216);     //  4,194,304
  u16* vtnp = (u16*)(ws + 20971520);     //  4,194,304

  // fused convert: 7,864,320 float4 units -> contiguous bf16 regions at ws+0
  cvt_all<<<30720, 256, 0, stream>>>((const float4*)x, (const float4*)ctx,
                                     (const float4*)Wq, (const float4*)Wk,
                                     (const float4*)Wv, (uint2*)ws);

  qgemm256<<<256, 512, 0, stream>>>(xb, Wqb, qnp);
  gemm_bt<<<dim3(8, 32), 256, 0, stream>>>(cb, Wkb, kvraw, 4096);
  kvbuild2<<<512, 256, 0, stream>>>(kvraw, knp, vtnp);
  attn4<<<dim3(32, 64), 256, 0, stream>>>(qnp, knp, vtnp, out);
}